// Round 3
// baseline (648.047 us; speedup 1.0000x reference)
//
#include <hip/hip_runtime.h>

// MultiHeadAttention_2207613190505 — round 3 (resubmit; rounds 1-2 hit GPU
// acquisition timeouts, kernel never ran). Full bf16 MFMA pipeline.
// B=1 S=2048 H=4096 NH=32 NKV=8 HD=128, causal, GQA n_rep=4.
// Pipeline: convert/transpose -> GEMM1 (QKV, fused N=6144) -> RoPE/split ->
//           flash attention -> GEMM2 (Wo) -> f32 out.

typedef unsigned short u16;
typedef __bf16 bf16x8 __attribute__((ext_vector_type(8)));
typedef float f32x4 __attribute__((ext_vector_type(4)));

#define S_TOK 2048
#define HID 4096
#define NQH 32
#define NKVH 8
#define HDIM 128

__device__ __forceinline__ u16 f2b(float f) {
  unsigned u = __builtin_bit_cast(unsigned, f);
  unsigned r = 0x7fffu + ((u >> 16) & 1u);
  return (u16)((u + r) >> 16);
}
__device__ __forceinline__ float b2f(u16 v) {
  return __builtin_bit_cast(float, ((unsigned)v) << 16);
}
__device__ __forceinline__ void gload16(const void* g, void* l) {
  __builtin_amdgcn_global_load_lds((const __attribute__((address_space(1))) void*)g,
                                   (__attribute__((address_space(3))) void*)l, 16, 0, 0);
}

// ---------------- convert f32 -> bf16 (X) ----------------
__global__ __launch_bounds__(256) void convert_f32_bf16(const float* __restrict__ in,
                                                        u16* __restrict__ out, int n4) {
  int i = blockIdx.x * 256 + threadIdx.x;
  if (i < n4) {
    float4 v = ((const float4*)in)[i];
    ushort4 o;
    o.x = f2b(v.x); o.y = f2b(v.y); o.z = f2b(v.z); o.w = f2b(v.w);
    ((ushort4*)out)[i] = o;
  }
}

// ---------------- transpose + convert: W[K=4096][N] f32 -> Wt[rowoff+n][4096] bf16 ----
__global__ __launch_bounds__(256) void transpose_convert(const float* __restrict__ W,
                                                         u16* __restrict__ Wt,
                                                         int N, int rowoff) {
  __shared__ float tile[32][33];
  const int tx = threadIdx.x, ty = threadIdx.y;  // (32,8)
  const int n0 = blockIdx.x * 32, k0 = blockIdx.y * 32;
#pragma unroll
  for (int j = 0; j < 4; ++j)
    tile[ty + 8 * j][tx] = W[(size_t)(k0 + ty + 8 * j) * N + n0 + tx];
  __syncthreads();
#pragma unroll
  for (int j = 0; j < 4; ++j)
    Wt[(size_t)(rowoff + n0 + ty + 8 * j) * 4096 + k0 + tx] = f2b(tile[tx][ty + 8 * j]);
}

// ---------------- GEMM: C[M][N] = A[M][K] * Bt[N][K]^T (bf16 in, f32 acc) ----------
// m97 structure: 128x128 tile, BK=32, 4 waves (2x2 of 64x64), global_load_lds w16.
template <bool F32OUT>
__global__ __launch_bounds__(256) void gemm_bf16(const u16* __restrict__ A,
                                                 const u16* __restrict__ Bt,
                                                 void* __restrict__ Cout,
                                                 int K, int N) {
  __shared__ __align__(16) u16 As[128 * 32];
  __shared__ __align__(16) u16 Bs[128 * 32];
  const int t = threadIdx.x;
  const int lane = t & 63;
  const int lo = lane & 15, hi = lane >> 4;
  const int wid = t >> 6;
  const int wr = wid >> 1, wc = wid & 1;
  const int bx = blockIdx.x, by = blockIdx.y;

  const u16* Ag = A + (size_t)(by * 128 + (t >> 2)) * K + (t & 3) * 8;
  const u16* Bg = Bt + (size_t)(bx * 128 + (t >> 2)) * K + (t & 3) * 8;

  const f32x4 zero = {0.f, 0.f, 0.f, 0.f};
  f32x4 acc[4][4];
#pragma unroll
  for (int m = 0; m < 4; ++m)
#pragma unroll
    for (int n = 0; n < 4; ++n) acc[m][n] = zero;

  for (int k0 = 0; k0 < K; k0 += 32) {
    __syncthreads();  // WAR: previous iter's LDS reads done
    gload16(Ag + k0, &As[t * 8]);
    gload16(Ag + (size_t)64 * K + k0, &As[2048 + t * 8]);
    gload16(Bg + k0, &Bs[t * 8]);
    gload16(Bg + (size_t)64 * K + k0, &Bs[2048 + t * 8]);
    __syncthreads();  // staging visible (vmcnt drained by compiler)

    bf16x8 af[4], bfr[4];
#pragma unroll
    for (int m = 0; m < 4; ++m)
      af[m] = *(const bf16x8*)&As[(wr * 64 + m * 16 + lo) * 32 + 8 * hi];
#pragma unroll
    for (int n = 0; n < 4; ++n)
      bfr[n] = *(const bf16x8*)&Bs[(wc * 64 + n * 16 + lo) * 32 + 8 * hi];
#pragma unroll
    for (int m = 0; m < 4; ++m)
#pragma unroll
      for (int n = 0; n < 4; ++n)
        acc[m][n] = __builtin_amdgcn_mfma_f32_16x16x32_bf16(af[m], bfr[n], acc[m][n], 0, 0, 0);
  }

#pragma unroll
  for (int m = 0; m < 4; ++m)
#pragma unroll
    for (int n = 0; n < 4; ++n)
#pragma unroll
      for (int r = 0; r < 4; ++r) {
        int row = by * 128 + wr * 64 + m * 16 + 4 * hi + r;
        int col = bx * 128 + wc * 64 + n * 16 + lo;
        if (F32OUT)
          ((float*)Cout)[(size_t)row * N + col] = acc[m][n][r];
        else
          ((u16*)Cout)[(size_t)row * N + col] = f2b(acc[m][n][r]);
      }
}

// ---------------- RoPE + split: C1[s][6144] -> Qh[32][S][128], Kh[8][S][128], Vt[8][128][S]
__global__ __launch_bounds__(256) void rope_split(const u16* __restrict__ C1,
                                                  const float* __restrict__ cosb,
                                                  const float* __restrict__ sinb,
                                                  u16* __restrict__ Qh,
                                                  u16* __restrict__ Kh,
                                                  u16* __restrict__ Vt) {
  int idx = blockIdx.x * 256 + threadIdx.x;  // 48 * 2048 * 64 total
  int slot = idx >> 17;
  int rem = idx & 131071;
  int s = rem >> 6;
  int d = rem & 63;
  if (slot < 32) {
    size_t base = (size_t)s * 6144 + slot * 128 + d;
    float x1 = b2f(C1[base]), x2 = b2f(C1[base + 64]);
    float c1 = cosb[s * 128 + d], s1 = sinb[s * 128 + d];
    float c2 = cosb[s * 128 + d + 64], s2 = sinb[s * 128 + d + 64];
    size_t ob = ((size_t)slot * S_TOK + s) * 128 + d;
    Qh[ob] = f2b(x1 * c1 - x2 * s1);
    Qh[ob + 64] = f2b(x2 * c2 + x1 * s2);
  } else if (slot < 40) {
    int hk = slot - 32;
    size_t base = (size_t)s * 6144 + 4096 + hk * 128 + d;
    float x1 = b2f(C1[base]), x2 = b2f(C1[base + 64]);
    float c1 = cosb[s * 128 + d], s1 = sinb[s * 128 + d];
    float c2 = cosb[s * 128 + d + 64], s2 = sinb[s * 128 + d + 64];
    size_t ob = ((size_t)hk * S_TOK + s) * 128 + d;
    Kh[ob] = f2b(x1 * c1 - x2 * s1);
    Kh[ob + 64] = f2b(x2 * c2 + x1 * s2);
  } else {
    int hk = slot - 40;
    size_t base = (size_t)s * 6144 + 5120 + hk * 128 + d;
    Vt[((size_t)(hk * 128 + d)) * S_TOK + s] = C1[base];
    Vt[((size_t)(hk * 128 + d + 64)) * S_TOK + s] = C1[base + 64];
  }
}

// ---------------- Flash attention (causal, GQA). One (head, 64-row Q block) per block.
// 4 waves x 16 q-rows, KVBLK=64, 16x16x32 MFMA, XOR-swizzled K/V LDS tiles.
__global__ __launch_bounds__(256) void attn_kernel(const u16* __restrict__ Qh,
                                                   const u16* __restrict__ Kh,
                                                   const u16* __restrict__ Vt,
                                                   u16* __restrict__ Attn) {
  __shared__ __align__(16) u16 Ks[64 * 128];       // [kv][d], d-bytes XOR-swizzled by kv&7
  __shared__ __align__(16) u16 Vs[128 * 64];       // [d][kv], kv-bytes XOR-swizzled by d&7
  __shared__ __align__(16) u16 Ps[4][16 * 80];     // per-wave P tile, row stride 80 (pad)
  const int t = threadIdx.x, lane = t & 63, wid = t >> 6;
  const int lo = lane & 15, hi = lane >> 4;
  const int qb = 31 - blockIdx.x;  // heavy blocks first
  const int h = blockIdx.y, hk = h >> 2;
  const float scale = 0.08838834764831845f;  // 1/sqrt(128)

  bf16x8 qf[4];
  {
    const int qrow = qb * 64 + wid * 16 + lo;
    const u16* qp = Qh + ((size_t)h * S_TOK + qrow) * 128 + 8 * hi;
#pragma unroll
    for (int c = 0; c < 4; ++c) qf[c] = *(const bf16x8*)(qp + c * 32);
  }
  const f32x4 zero = {0.f, 0.f, 0.f, 0.f};
  f32x4 acc[8];
#pragma unroll
  for (int d = 0; d < 8; ++d) acc[d] = zero;
  float m_r[4], l_r[4];
#pragma unroll
  for (int r = 0; r < 4; ++r) { m_r[r] = -1e30f; l_r[r] = 0.f; }
  const int qg0 = qb * 64 + wid * 16 + 4 * hi;  // + r = global q row

  for (int tkv = 0; tkv <= qb; ++tkv) {
    const int s0 = tkv * 64;
    __syncthreads();
#pragma unroll
    for (int j = 0; j < 4; ++j) {  // stage K: 64x128
      int e = j * 2048 + t * 8;
      int kv = e >> 7;
      int dsrc = ((t & 15) * 8) ^ ((kv & 7) << 3);
      gload16(Kh + ((size_t)hk * S_TOK + s0 + kv) * 128 + dsrc, &Ks[e]);
    }
#pragma unroll
    for (int j = 0; j < 4; ++j) {  // stage V^T: 128x64
      int e = j * 2048 + t * 8;
      int d = e >> 6;
      int kvsrc = ((t & 7) * 8) ^ ((d & 7) << 3);
      gload16(Vt + ((size_t)hk * 128 + d) * S_TOK + s0 + kvsrc, &Vs[e]);
    }
    __syncthreads();

    // QK^T: S[q][kv], 16 MFMA
    f32x4 sf[4];
#pragma unroll
    for (int sub = 0; sub < 4; ++sub) {
      sf[sub] = zero;
#pragma unroll
      for (int c = 0; c < 4; ++c) {
        bf16x8 kf = *(const bf16x8*)&Ks[(sub * 16 + lo) * 128 + ((c * 32 + 8 * hi) ^ ((lo & 7) << 3))];
        sf[sub] = __builtin_amdgcn_mfma_f32_16x16x32_bf16(qf[c], kf, sf[sub], 0, 0, 0);
      }
    }

    const bool diag = (tkv == qb);
    float p[4][4], alpha[4];
#pragma unroll
    for (int r = 0; r < 4; ++r) {
      float sv[4];
      float mx = -1e30f;
#pragma unroll
      for (int sub = 0; sub < 4; ++sub) {
        float v = sf[sub][r] * scale;
        if (diag && (s0 + sub * 16 + lo) > (qg0 + r)) v = -1e9f;
        sv[sub] = v;
        mx = fmaxf(mx, v);
      }
      mx = fmaxf(mx, __shfl_xor(mx, 1));
      mx = fmaxf(mx, __shfl_xor(mx, 2));
      mx = fmaxf(mx, __shfl_xor(mx, 4));
      mx = fmaxf(mx, __shfl_xor(mx, 8));
      float mn = fmaxf(m_r[r], mx);
      alpha[r] = __expf(m_r[r] - mn);
      m_r[r] = mn;
      float rs = 0.f;
#pragma unroll
      for (int sub = 0; sub < 4; ++sub) {
        float pe = __expf(sv[sub] - mn);
        p[sub][r] = pe;
        rs += pe;
      }
      rs += __shfl_xor(rs, 1);
      rs += __shfl_xor(rs, 2);
      rs += __shfl_xor(rs, 4);
      rs += __shfl_xor(rs, 8);
      l_r[r] = l_r[r] * alpha[r] + rs;
    }
#pragma unroll
    for (int d = 0; d < 8; ++d)
#pragma unroll
      for (int r = 0; r < 4; ++r) acc[d][r] *= alpha[r];

    // P -> LDS (transpose to A-fragment layout)
#pragma unroll
    for (int sub = 0; sub < 4; ++sub)
#pragma unroll
      for (int r = 0; r < 4; ++r)
        Ps[wid][(4 * hi + r) * 80 + sub * 16 + lo] = f2b(p[sub][r]);
    asm volatile("s_waitcnt lgkmcnt(0)" ::: "memory");

    // PV: 16 MFMA
#pragma unroll
    for (int kc = 0; kc < 2; ++kc) {
      bf16x8 pa = *(const bf16x8*)&Ps[wid][lo * 80 + kc * 32 + 8 * hi];
#pragma unroll
      for (int d = 0; d < 8; ++d) {
        bf16x8 vf = *(const bf16x8*)&Vs[(d * 16 + lo) * 64 + ((kc * 32 + 8 * hi) ^ ((lo & 7) << 3))];
        acc[d] = __builtin_amdgcn_mfma_f32_16x16x32_bf16(pa, vf, acc[d], 0, 0, 0);
      }
    }
  }

#pragma unroll
  for (int d = 0; d < 8; ++d)
#pragma unroll
    for (int r = 0; r < 4; ++r) {
      float o = acc[d][r] / l_r[r];
      int row = qb * 64 + wid * 16 + 4 * hi + r;
      int col = h * 128 + d * 16 + lo;
      Attn[(size_t)row * 4096 + col] = f2b(o);
    }
}

// ---------------- host ----------------
extern "C" void kernel_launch(void* const* d_in, const int* in_sizes, int n_in,
                              void* d_out, int out_size, void* d_ws, size_t ws_size,
                              hipStream_t stream) {
  (void)in_sizes; (void)n_in; (void)out_size; (void)ws_size;
  const float* X = (const float*)d_in[0];
  const float* cosb = (const float*)d_in[3];
  const float* sinb = (const float*)d_in[4];
  const float* Wq = (const float*)d_in[5];
  const float* Wk = (const float*)d_in[6];
  const float* Wv = (const float*)d_in[7];
  const float* Wo = (const float*)d_in[8];
  float* out = (float*)d_out;
  char* ws = (char*)d_ws;

  // workspace layout (96 MiB peak, with aliasing)
  u16* Xb    = (u16*)(ws + 0);          // 16,777,216 B
  u16* Wqkvt = (u16*)(ws + 16777216);   // 50,331,648 B  [6144][4096]
  u16* Wot   = Wqkvt;                   // alias: used only after gemm1
  u16* C1    = (u16*)(ws + 67108864);   // 25,165,824 B  [2048][6144]
  u16* Kh    = (u16*)(ws + 92274688);   //  4,194,304 B  [8][2048][128]
  u16* Vt    = (u16*)(ws + 96468992);   //  4,194,304 B  [8][128][2048]
  u16* Qh    = Xb;                      // alias: Xb dead after gemm1
  u16* Attn  = C1;                      // alias: C1 dead after rope

  convert_f32_bf16<<<8192, 256, 0, stream>>>(X, Xb, 2097152);
  transpose_convert<<<dim3(128, 128), dim3(32, 8), 0, stream>>>(Wq, Wqkvt, 4096, 0);
  transpose_convert<<<dim3(32, 128), dim3(32, 8), 0, stream>>>(Wk, Wqkvt, 1024, 4096);
  transpose_convert<<<dim3(32, 128), dim3(32, 8), 0, stream>>>(Wv, Wqkvt, 1024, 5120);
  gemm_bf16<false><<<dim3(48, 16), 256, 0, stream>>>(Xb, Wqkvt, C1, 4096, 6144);
  transpose_convert<<<dim3(128, 128), dim3(32, 8), 0, stream>>>(Wo, Wot, 4096, 0);
  rope_split<<<24576, 256, 0, stream>>>(C1, cosb, sinb, Qh, Kh, Vt);
  attn_kernel<<<dim3(32, 32), 256, 0, stream>>>(Qh, Kh, Vt, Attn);
  gemm_bf16<true><<<dim3(32, 16), 256, 0, stream>>>(Attn, Wot, out, 4096, 4096);
}

// Round 11
// 613.348 us; speedup vs baseline: 1.0566x; 1.0566x over previous
//
#include <hip/hip_runtime.h>

// MultiHeadAttention_2207613190505 — round 11 (resubmit; rounds 4-10 infra
// failures, the attn rewrite has never run).
// Changes vs round 3 (which passed, 648us, attn=183us @ 7.6% MfmaUtil):
//  - swapped QK^T: mfma(K,Q) -> per-lane row softmax (shuffles 32 -> ~10/tile)
//  - Ps packed ushort4 writes, stride 72 (was scalar u16, stride 80, 8-way conflict)
//  - K/V double-buffered staging, ONE barrier per KV tile (stage-early overlap)
// GEMMs / rope / transposes unchanged.

typedef unsigned short u16;
typedef __bf16 bf16x8 __attribute__((ext_vector_type(8)));
typedef float f32x4 __attribute__((ext_vector_type(4)));

#define S_TOK 2048
#define HID 4096
#define NQH 32
#define NKVH 8
#define HDIM 128

__device__ __forceinline__ u16 f2b(float f) {
  unsigned u = __builtin_bit_cast(unsigned, f);
  unsigned r = 0x7fffu + ((u >> 16) & 1u);
  return (u16)((u + r) >> 16);
}
__device__ __forceinline__ float b2f(u16 v) {
  return __builtin_bit_cast(float, ((unsigned)v) << 16);
}
__device__ __forceinline__ void gload16(const void* g, void* l) {
  __builtin_amdgcn_global_load_lds((const __attribute__((address_space(1))) void*)g,
                                   (__attribute__((address_space(3))) void*)l, 16, 0, 0);
}

// ---------------- convert f32 -> bf16 (X) ----------------
__global__ __launch_bounds__(256) void convert_f32_bf16(const float* __restrict__ in,
                                                        u16* __restrict__ out, int n4) {
  int i = blockIdx.x * 256 + threadIdx.x;
  if (i < n4) {
    float4 v = ((const float4*)in)[i];
    ushort4 o;
    o.x = f2b(v.x); o.y = f2b(v.y); o.z = f2b(v.z); o.w = f2b(v.w);
    ((ushort4*)out)[i] = o;
  }
}

// ---------------- transpose + convert: W[K=4096][N] f32 -> Wt[rowoff+n][4096] bf16 ----
__global__ __launch_bounds__(256) void transpose_convert(const float* __restrict__ W,
                                                         u16* __restrict__ Wt,
                                                         int N, int rowoff) {
  __shared__ float tile[32][33];
  const int tx = threadIdx.x, ty = threadIdx.y;  // (32,8)
  const int n0 = blockIdx.x * 32, k0 = blockIdx.y * 32;
#pragma unroll
  for (int j = 0; j < 4; ++j)
    tile[ty + 8 * j][tx] = W[(size_t)(k0 + ty + 8 * j) * N + n0 + tx];
  __syncthreads();
#pragma unroll
  for (int j = 0; j < 4; ++j)
    Wt[(size_t)(rowoff + n0 + ty + 8 * j) * 4096 + k0 + tx] = f2b(tile[tx][ty + 8 * j]);
}

// ---------------- GEMM: C[M][N] = A[M][K] * Bt[N][K]^T (bf16 in, f32 acc) ----------
template <bool F32OUT>
__global__ __launch_bounds__(256) void gemm_bf16(const u16* __restrict__ A,
                                                 const u16* __restrict__ Bt,
                                                 void* __restrict__ Cout,
                                                 int K, int N) {
  __shared__ __align__(16) u16 As[128 * 32];
  __shared__ __align__(16) u16 Bs[128 * 32];
  const int t = threadIdx.x;
  const int lane = t & 63;
  const int lo = lane & 15, hi = lane >> 4;
  const int wid = t >> 6;
  const int wr = wid >> 1, wc = wid & 1;
  const int bx = blockIdx.x, by = blockIdx.y;

  const u16* Ag = A + (size_t)(by * 128 + (t >> 2)) * K + (t & 3) * 8;
  const u16* Bg = Bt + (size_t)(bx * 128 + (t >> 2)) * K + (t & 3) * 8;

  const f32x4 zero = {0.f, 0.f, 0.f, 0.f};
  f32x4 acc[4][4];
#pragma unroll
  for (int m = 0; m < 4; ++m)
#pragma unroll
    for (int n = 0; n < 4; ++n) acc[m][n] = zero;

  for (int k0 = 0; k0 < K; k0 += 32) {
    __syncthreads();
    gload16(Ag + k0, &As[t * 8]);
    gload16(Ag + (size_t)64 * K + k0, &As[2048 + t * 8]);
    gload16(Bg + k0, &Bs[t * 8]);
    gload16(Bg + (size_t)64 * K + k0, &Bs[2048 + t * 8]);
    __syncthreads();

    bf16x8 af[4], bfr[4];
#pragma unroll
    for (int m = 0; m < 4; ++m)
      af[m] = *(const bf16x8*)&As[(wr * 64 + m * 16 + lo) * 32 + 8 * hi];
#pragma unroll
    for (int n = 0; n < 4; ++n)
      bfr[n] = *(const bf16x8*)&Bs[(wc * 64 + n * 16 + lo) * 32 + 8 * hi];
#pragma unroll
    for (int m = 0; m < 4; ++m)
#pragma unroll
      for (int n = 0; n < 4; ++n)
        acc[m][n] = __builtin_amdgcn_mfma_f32_16x16x32_bf16(af[m], bfr[n], acc[m][n], 0, 0, 0);
  }

#pragma unroll
  for (int m = 0; m < 4; ++m)
#pragma unroll
    for (int n = 0; n < 4; ++n)
#pragma unroll
      for (int r = 0; r < 4; ++r) {
        int row = by * 128 + wr * 64 + m * 16 + 4 * hi + r;
        int col = bx * 128 + wc * 64 + n * 16 + lo;
        if (F32OUT)
          ((float*)Cout)[(size_t)row * N + col] = acc[m][n][r];
        else
          ((u16*)Cout)[(size_t)row * N + col] = f2b(acc[m][n][r]);
      }
}

// ---------------- RoPE + split: C1[s][6144] -> Qh[32][S][128], Kh[8][S][128], Vt[8][128][S]
__global__ __launch_bounds__(256) void rope_split(const u16* __restrict__ C1,
                                                  const float* __restrict__ cosb,
                                                  const float* __restrict__ sinb,
                                                  u16* __restrict__ Qh,
                                                  u16* __restrict__ Kh,
                                                  u16* __restrict__ Vt) {
  int idx = blockIdx.x * 256 + threadIdx.x;
  int slot = idx >> 17;
  int rem = idx & 131071;
  int s = rem >> 6;
  int d = rem & 63;
  if (slot < 32) {
    size_t base = (size_t)s * 6144 + slot * 128 + d;
    float x1 = b2f(C1[base]), x2 = b2f(C1[base + 64]);
    float c1 = cosb[s * 128 + d], s1 = sinb[s * 128 + d];
    float c2 = cosb[s * 128 + d + 64], s2 = sinb[s * 128 + d + 64];
    size_t ob = ((size_t)slot * S_TOK + s) * 128 + d;
    Qh[ob] = f2b(x1 * c1 - x2 * s1);
    Qh[ob + 64] = f2b(x2 * c2 + x1 * s2);
  } else if (slot < 40) {
    int hk = slot - 32;
    size_t base = (size_t)s * 6144 + 4096 + hk * 128 + d;
    float x1 = b2f(C1[base]), x2 = b2f(C1[base + 64]);
    float c1 = cosb[s * 128 + d], s1 = sinb[s * 128 + d];
    float c2 = cosb[s * 128 + d + 64], s2 = sinb[s * 128 + d + 64];
    size_t ob = ((size_t)hk * S_TOK + s) * 128 + d;
    Kh[ob] = f2b(x1 * c1 - x2 * s1);
    Kh[ob + 64] = f2b(x2 * c2 + x1 * s2);
  } else {
    int hk = slot - 40;
    size_t base = (size_t)s * 6144 + 5120 + hk * 128 + d;
    Vt[((size_t)(hk * 128 + d)) * S_TOK + s] = C1[base];
    Vt[((size_t)(hk * 128 + d + 64)) * S_TOK + s] = C1[base + 64];
  }
}

// ---------------- Flash attention (causal, GQA) — swapped-QK^T, per-lane softmax,
// double-buffered K/V staging with one barrier per KV tile.
__global__ __launch_bounds__(256) void attn_kernel(const u16* __restrict__ Qh,
                                                   const u16* __restrict__ Kh,
                                                   const u16* __restrict__ Vt,
                                                   u16* __restrict__ Attn) {
  __shared__ __align__(16) u16 Ks[2][64 * 128];  // [buf][kv][d], d XOR-swizzled by kv&7
  __shared__ __align__(16) u16 Vs[2][128 * 64];  // [buf][d][kv], kv XOR-swizzled by d&7
  __shared__ __align__(16) u16 Ps[4][16 * 72];   // per-wave P[q][kv], q-stride 72
  const int t = threadIdx.x, lane = t & 63, wid = t >> 6;
  const int lo = lane & 15, hi = lane >> 4;
  const int qb = 31 - blockIdx.x;  // heavy blocks first
  const int h = blockIdx.y, hk = h >> 2;
  const float scale = 0.08838834764831845f;  // 1/sqrt(128)

  const int q_glob = qb * 64 + wid * 16 + lo;  // this lane's q row (softmax owner)

  bf16x8 qf[4];
  {
    const u16* qp = Qh + ((size_t)h * S_TOK + q_glob) * 128 + 8 * hi;
#pragma unroll
    for (int c = 0; c < 4; ++c) qf[c] = *(const bf16x8*)(qp + c * 32);
  }
  const f32x4 zero = {0.f, 0.f, 0.f, 0.f};
  f32x4 acc[8];
#pragma unroll
  for (int d = 0; d < 8; ++d) acc[d] = zero;
  float m_run = -1e30f, l_run = 0.f;

#define STAGE(buf, tkv_)                                                          \
  {                                                                               \
    const int s0_ = (tkv_)*64;                                                    \
    _Pragma("unroll") for (int j = 0; j < 4; ++j) {                               \
      int e = j * 2048 + t * 8;                                                   \
      int kv = e >> 7;                                                            \
      int dsrc = ((t & 15) * 8) ^ ((kv & 7) << 3);                                \
      gload16(Kh + ((size_t)hk * S_TOK + s0_ + kv) * 128 + dsrc, &Ks[buf][e]);    \
    }                                                                             \
    _Pragma("unroll") for (int j = 0; j < 4; ++j) {                               \
      int e = j * 2048 + t * 8;                                                   \
      int d = e >> 6;                                                             \
      int kvsrc = ((t & 7) * 8) ^ ((d & 7) << 3);                                 \
      gload16(Vt + ((size_t)hk * 128 + d) * S_TOK + s0_ + kvsrc, &Vs[buf][e]);    \
    }                                                                             \
  }

  STAGE(0, 0);
  __syncthreads();  // prologue: tile 0 staged (vmcnt drained by barrier)

  const int nt = qb + 1;
  for (int tkv = 0; tkv < nt; ++tkv) {
    const int cur = tkv & 1;
    if (tkv + 1 < nt) STAGE(cur ^ 1, tkv + 1);  // prefetch next tile (hidden under compute)
    const int s0 = tkv * 64;

    // QK^T swapped: sf = mfma(K, Q) -> D[row=kv_local=4hi+r (+16*sub)][col=q=lo]
    f32x4 sf[4];
#pragma unroll
    for (int sub = 0; sub < 4; ++sub) {
      sf[sub] = zero;
#pragma unroll
      for (int c = 0; c < 4; ++c) {
        bf16x8 kf = *(const bf16x8*)&Ks[cur][(sub * 16 + lo) * 128 + ((c * 32 + 8 * hi) ^ ((lo & 7) << 3))];
        sf[sub] = __builtin_amdgcn_mfma_f32_16x16x32_bf16(kf, qf[c], sf[sub], 0, 0, 0);
      }
    }

    // per-lane online softmax over this lane's 16 kv entries (kv = sub*16+4hi+r)
    float sv[4][4];
    float mx = -3e38f;
    if (tkv == qb) {
#pragma unroll
      for (int sub = 0; sub < 4; ++sub)
#pragma unroll
        for (int r = 0; r < 4; ++r) {
          float v = sf[sub][r] * scale;
          if (s0 + sub * 16 + 4 * hi + r > q_glob) v = -1e9f;
          sv[sub][r] = v;
          mx = fmaxf(mx, v);
        }
    } else {
#pragma unroll
      for (int sub = 0; sub < 4; ++sub)
#pragma unroll
        for (int r = 0; r < 4; ++r) {
          float v = sf[sub][r] * scale;
          sv[sub][r] = v;
          mx = fmaxf(mx, v);
        }
    }
    // combine the 4 hi-groups (same q row lives in lanes lo, lo+16, lo+32, lo+48)
    mx = fmaxf(mx, __shfl_xor(mx, 16));
    mx = fmaxf(mx, __shfl_xor(mx, 32));
    const float mn = fmaxf(m_run, mx);
    const float alpha = __expf(m_run - mn);
    m_run = mn;
    float rs = 0.f;
#pragma unroll
    for (int sub = 0; sub < 4; ++sub)
#pragma unroll
      for (int r = 0; r < 4; ++r) {
        float pe = __expf(sv[sub][r] - mn);
        sv[sub][r] = pe;
        rs += pe;
      }
    rs += __shfl_xor(rs, 16);
    rs += __shfl_xor(rs, 32);
    l_run = l_run * alpha + rs;

    // P -> LDS, packed (4 consecutive kv per write): Ps[q=lo][kv = sub*16+4hi+r]
#pragma unroll
    for (int sub = 0; sub < 4; ++sub) {
      ushort4 w;
      w.x = f2b(sv[sub][0]); w.y = f2b(sv[sub][1]);
      w.z = f2b(sv[sub][2]); w.w = f2b(sv[sub][3]);
      *(ushort4*)&Ps[wid][lo * 72 + sub * 16 + 4 * hi] = w;
    }
    asm volatile("s_waitcnt lgkmcnt(0)" ::: "memory");
    __builtin_amdgcn_sched_barrier(0);

    // gather alpha for PV accumulator rows (row q-local = 4hi+r -> lane lo=4hi+r)
    float af4[4];
#pragma unroll
    for (int r = 0; r < 4; ++r) af4[r] = __shfl(alpha, 4 * hi + r);
#pragma unroll
    for (int d = 0; d < 8; ++d)
#pragma unroll
      for (int r = 0; r < 4; ++r) acc[d][r] *= af4[r];

    // PV: A = P[q=lo][kv], B = V^T rows
#pragma unroll
    for (int kc = 0; kc < 2; ++kc) {
      bf16x8 pa = *(const bf16x8*)&Ps[wid][lo * 72 + kc * 32 + 8 * hi];
#pragma unroll
      for (int d = 0; d < 8; ++d) {
        bf16x8 vf = *(const bf16x8*)&Vs[cur][(d * 16 + lo) * 64 + ((kc * 32 + 8 * hi) ^ ((lo & 7) << 3))];
        acc[d] = __builtin_amdgcn_mfma_f32_16x16x32_bf16(pa, vf, acc[d], 0, 0, 0);
      }
    }
    __syncthreads();  // all waves done with buf cur; next tile's loads drained
  }
#undef STAGE

  float lr[4];
#pragma unroll
  for (int r = 0; r < 4; ++r) lr[r] = __shfl(l_run, 4 * hi + r);
#pragma unroll
  for (int d = 0; d < 8; ++d)
#pragma unroll
    for (int r = 0; r < 4; ++r) {
      float o = acc[d][r] / lr[r];
      int row = qb * 64 + wid * 16 + 4 * hi + r;
      int col = h * 128 + d * 16 + lo;
      Attn[(size_t)row * 4096 + col] = f2b(o);
    }
}

// ---------------- host ----------------
extern "C" void kernel_launch(void* const* d_in, const int* in_sizes, int n_in,
                              void* d_out, int out_size, void* d_ws, size_t ws_size,
                              hipStream_t stream) {
  (void)in_sizes; (void)n_in; (void)out_size; (void)ws_size;
  const float* X = (const float*)d_in[0];
  const float* cosb = (const float*)d_in[3];
  const float* sinb = (const float*)d_in[4];
  const float* Wq = (const float*)d_in[5];
  const float* Wk = (const float*)d_in[6];
  const float* Wv = (const float*)d_in[7];
  const float* Wo = (const float*)d_in[8];
  float* out = (float*)d_out;
  char* ws = (char*)d_ws;

  u16* Xb    = (u16*)(ws + 0);          // 16,777,216 B
  u16* Wqkvt = (u16*)(ws + 16777216);   // 50,331,648 B  [6144][4096]
  u16* Wot   = Wqkvt;                   // alias: used only after gemm1
  u16* C1    = (u16*)(ws + 67108864);   // 25,165,824 B  [2048][6144]
  u16* Kh    = (u16*)(ws + 92274688);   //  4,194,304 B  [8][2048][128]
  u16* Vt    = (u16*)(ws + 96468992);   //  4,194,304 B  [8][128][2048]
  u16* Qh    = Xb;                      // alias: Xb dead after gemm1
  u16* Attn  = C1;                      // alias: C1 dead after rope

  convert_f32_bf16<<<8192, 256, 0, stream>>>(X, Xb, 2097152);
  transpose_convert<<<dim3(128, 128), dim3(32, 8), 0, stream>>>(Wq, Wqkvt, 4096, 0);
  transpose_convert<<<dim3(32, 128), dim3(32, 8), 0, stream>>>(Wk, Wqkvt, 1024, 4096);
  transpose_convert<<<dim3(32, 128), dim3(32, 8), 0, stream>>>(Wv, Wqkvt, 1024, 5120);
  gemm_bf16<false><<<dim3(48, 16), 256, 0, stream>>>(Xb, Wqkvt, C1, 4096, 6144);
  transpose_convert<<<dim3(128, 128), dim3(32, 8), 0, stream>>>(Wo, Wot, 4096, 0);
  rope_split<<<24576, 256, 0, stream>>>(C1, cosb, sinb, Qh, Kh, Vt);
  attn_kernel<<<dim3(32, 32), 256, 0, stream>>>(Qh, Kh, Vt, Attn);
  gemm_bf16<true><<<dim3(32, 16), 256, 0, stream>>>(Attn, Wot, out, 4096, 4096);
}